// Round 2
// baseline (1014.508 us; speedup 1.0000x reference)
//
#include <hip/hip_runtime.h>

// Problem dims
constexpr int NS   = 16;    // batch
constexpr int DIM  = 32;    // in_dim == out_dim
constexpr int FEA  = 192;   // in_f == out_f
constexpr int ELEMS = DIM * FEA;   // 6144 per sample

// epass tiling
constexpr int SPLIT   = 4;              // f-splits per o
constexpr int FPB     = FEA / SPLIT;    // 48 f per block
constexpr int FCHUNK  = 16;             // f per LDS stage
constexpr int NCHUNKS = FPB / FCHUNK;   // 3
constexpr int ROWPAD  = 20;             // 16 floats (n) + 4 pad
constexpr int TPB     = 512;            // epass threads per block
constexpr int REDSTRIDE = 36;           // reduce row stride (16B aligned, 2-way banks)
constexpr int REDB      = 16 * 8 * REDSTRIDE;  // 4608 floats per (A/B) half

__device__ __forceinline__ void fma4(float4& a, float x, const float4& t) {
    a.x = fmaf(x, t.x, a.x);
    a.y = fmaf(x, t.y, a.y);
    a.z = fmaf(x, t.z, a.z);
    a.w = fmaf(x, t.w, a.w);
}

// Weighted contraction:
//   y[n, D, O] = sum_{I=0..31, F} X[n,I,F] * W[I][F][O][D] * A[F][O]
// W layout: [32][192][192][32] (D contiguous)
// xt layout: [F][I][n] (n contiguous, 16)
// Output partials: out[s][O][n*32+D]  (512 floats per (s,O))
// Thread map: tid = i*16 + nh*8 + dq.  Each thread: 8 n (nh half) x 4 d (dq quad).
template <bool DUAL>
__global__ __launch_bounds__(TPB, 4) void epass_kernel(
    const float* __restrict__ W, const float* __restrict__ xt,
    const float* __restrict__ A1, const float* __restrict__ A2,
    float* __restrict__ outA, float* __restrict__ outB)
{
    __shared__ float smem[FCHUNK * DIM * ROWPAD];  // 10240 floats (40 KB), reused for reduce
    __shared__ float acol[2][FPB];

    const int tid = threadIdx.x;
    const int o   = blockIdx.x >> 2;          // output O index
    const int s   = blockIdx.x & (SPLIT - 1); // f-split
    const int dq  = tid & 7;                  // D quad (0..7)
    const int nh  = (tid >> 3) & 1;           // n half (0..1)
    const int i   = tid >> 4;                 // contraction I (0..31)
    const int fBase = s * FPB;

    for (int j = tid; j < FPB; j += TPB) {
        acol[0][j] = A1[(fBase + j) * FEA + o];
        if (DUAL) acol[1][j] = A2[(fBase + j) * FEA + o];
    }

    float4 accA[8];
    float4 accB[8];
#pragma unroll
    for (int n = 0; n < 8; ++n) {
        accA[n] = make_float4(0.f, 0.f, 0.f, 0.f);
        if (DUAL) accB[n] = make_float4(0.f, 0.f, 0.f, 0.f);
    }

    const float* wp = W + (size_t)(((i * FEA + fBase) * FEA + o) * DIM + dq * 4);
    float4 tnext = *(const float4*)wp;   // prefetch carried across chunk seams

    for (int c = 0; c < NCHUNKS; ++c) {
        __syncthreads();
        // Stage x chunk: 16 f x 32 i x 16 n = 8192 floats, contiguous in xt
        const float4* src = (const float4*)(xt + (size_t)(fBase + c * FCHUNK) * (DIM * NS));
#pragma unroll
        for (int q = 0; q < 4; ++q) {
            int lin = q * TPB + tid;            // quad index, 2048 total
            float4 v = src[lin];
            *(float4*)&smem[(lin >> 2) * ROWPAD + (lin & 3) * 4] = v;
        }
        __syncthreads();

#pragma unroll
        for (int fl = 0; fl < FCHUNK; ++fl) {
            float4 t4 = tnext;
            wp += FEA * DIM;                    // advance one f (6144 floats)
            if (fl != FCHUNK - 1 || c != NCHUNKS - 1) tnext = *(const float4*)wp;

            const float a1 = acol[0][c * FCHUNK + fl];
            float4 ta = make_float4(t4.x * a1, t4.y * a1, t4.z * a1, t4.w * a1);
            float4 tb;
            if (DUAL) {
                const float a2 = acol[1][c * FCHUNK + fl];
                tb = make_float4(t4.x * a2, t4.y * a2, t4.z * a2, t4.w * a2);
            }

            const float* xr = &smem[(fl * DIM + i) * ROWPAD + nh * 8];
            float4 xv0 = *(const float4*)xr;
            float4 xv1 = *(const float4*)(xr + 4);
            fma4(accA[0], xv0.x, ta);
            fma4(accA[1], xv0.y, ta);
            fma4(accA[2], xv0.z, ta);
            fma4(accA[3], xv0.w, ta);
            fma4(accA[4], xv1.x, ta);
            fma4(accA[5], xv1.y, ta);
            fma4(accA[6], xv1.z, ta);
            fma4(accA[7], xv1.w, ta);
            if (DUAL) {
                fma4(accB[0], xv0.x, tb);
                fma4(accB[1], xv0.y, tb);
                fma4(accB[2], xv0.z, tb);
                fma4(accB[3], xv0.w, tb);
                fma4(accB[4], xv1.x, tb);
                fma4(accB[5], xv1.y, tb);
                fma4(accB[6], xv1.z, tb);
                fma4(accB[7], xv1.w, tb);
            }
        }
    }

    // Reduce over i-low-2 (lane bits 4,5)
#pragma unroll
    for (int m = 16; m <= 32; m <<= 1) {
#pragma unroll
        for (int n = 0; n < 8; ++n) {
            accA[n].x += __shfl_xor(accA[n].x, m);
            accA[n].y += __shfl_xor(accA[n].y, m);
            accA[n].z += __shfl_xor(accA[n].z, m);
            accA[n].w += __shfl_xor(accA[n].w, m);
            if (DUAL) {
                accB[n].x += __shfl_xor(accB[n].x, m);
                accB[n].y += __shfl_xor(accB[n].y, m);
                accB[n].z += __shfl_xor(accB[n].z, m);
                accB[n].w += __shfl_xor(accB[n].w, m);
            }
        }
    }

    const int lane = tid & 63;
    const int w    = tid >> 6;     // wave = i high 3 bits
    float* red = smem;             // reuse staging LDS

    __syncthreads();
    if ((lane & 48) == 0) {
        const int base = (w * 16 + nh * 8 + dq) * REDSTRIDE;
#pragma unroll
        for (int n = 0; n < 8; ++n) {
            *(float4*)&red[base + n * 4] = accA[n];
            if (DUAL) *(float4*)&red[REDB + base + n * 4] = accB[n];
        }
    }
    __syncthreads();
    {
        const int h = tid;                 // 0..511 == NS*DIM
        const int n = h >> 5, d = h & 31;
        const int base = ((n >> 3) * 8 + (d >> 2)) * REDSTRIDE + (n & 7) * 4 + (d & 3);
        float v = 0.f, vb = 0.f;
#pragma unroll
        for (int w2 = 0; w2 < 8; ++w2) {
            v += red[w2 * 16 * REDSTRIDE + base];
            if (DUAL) vb += red[REDB + w2 * 16 * REDSTRIDE + base];
        }
        outA[(size_t)(s * FEA + o) * (NS * DIM) + h] = v;
        if (DUAL) outB[(size_t)(s * FEA + o) * (NS * DIM) + h] = vb;
    }
}

// ---- small helpers -------------------------------------------------------

__device__ __forceinline__ float2 block_meanrstd(float s1, float s2, int tid, float* red8) {
#pragma unroll
    for (int m = 1; m < 64; m <<= 1) {
        s1 += __shfl_xor(s1, m);
        s2 += __shfl_xor(s2, m);
    }
    if ((tid & 63) == 0) {
        red8[(tid >> 6) * 2]     = s1;
        red8[(tid >> 6) * 2 + 1] = s2;
    }
    __syncthreads();
    s1 = red8[0] + red8[2] + red8[4] + red8[6];
    s2 = red8[1] + red8[3] + red8[5] + red8[7];
    float mean = s1 * (1.0f / ELEMS);
    float var  = s2 * (1.0f / ELEMS) - mean * mean;
    return make_float2(mean, rsqrtf(var + 1e-5f));
}

// h1 = LN(sum_s pA); writes natural [n][D][O] and transposed [O][D][n]
__global__ __launch_bounds__(256) void reduce_ln_h1(
    const float* __restrict__ p, float* __restrict__ h1, float* __restrict__ h1t)
{
    __shared__ float vals[ELEMS];
    __shared__ float red8[8];
    const int n = blockIdx.x, tid = threadIdx.x;
    float s1 = 0.f, s2 = 0.f;
    for (int e = tid; e < ELEMS; e += 256) {
        int d = e / FEA, o = e % FEA;
        float v = 0.f;
#pragma unroll
        for (int sp = 0; sp < SPLIT; ++sp)
            v += p[(size_t)(sp * FEA + o) * (NS * DIM) + n * DIM + d];
        vals[e] = v; s1 += v; s2 += v * v;
    }
    float2 mr = block_meanrstd(s1, s2, tid, red8);
    for (int e = tid; e < ELEMS; e += 256) {
        float v = (vals[e] - mr.x) * mr.y;
        h1[n * ELEMS + e] = v;
        int d = e / FEA, o = e % FEA;
        h1t[(o * DIM + d) * NS + n] = v;
    }
}

// h2 = LN(0.5*(xs1 + sum_s pC)); writes transposed only
__global__ __launch_bounds__(256) void reduce_ln_h2(
    const float* __restrict__ p, const float* __restrict__ xs1, float* __restrict__ h2t)
{
    __shared__ float vals[ELEMS];
    __shared__ float red8[8];
    const int n = blockIdx.x, tid = threadIdx.x;
    float s1 = 0.f, s2 = 0.f;
    for (int e = tid; e < ELEMS; e += 256) {
        int d = e / FEA, o = e % FEA;
        float v = 0.f;
#pragma unroll
        for (int sp = 0; sp < SPLIT; ++sp)
            v += p[(size_t)(sp * FEA + o) * (NS * DIM) + n * DIM + d];
        v = 0.5f * (v + xs1[n * ELEMS + e]);
        vals[e] = v; s1 += v; s2 += v * v;
    }
    float2 mr = block_meanrstd(s1, s2, tid, red8);
    for (int e = tid; e < ELEMS; e += 256) {
        float v = (vals[e] - mr.x) * mr.y;
        int d = e / FEA, o = e % FEA;
        h2t[(o * DIM + d) * NS + n] = v;
    }
}

// out = LN((sum_s pB + h1t1 + sum_s pD)/3); natural layout
__global__ __launch_bounds__(256) void final_ln(
    const float* __restrict__ pB, const float* __restrict__ pD,
    const float* __restrict__ h1t1, float* __restrict__ out)
{
    __shared__ float vals[ELEMS];
    __shared__ float red8[8];
    const int n = blockIdx.x, tid = threadIdx.x;
    float s1 = 0.f, s2 = 0.f;
    for (int e = tid; e < ELEMS; e += 256) {
        int d = e / FEA, o = e % FEA;
        float v = 0.f;
#pragma unroll
        for (int sp = 0; sp < SPLIT; ++sp) {
            v += pB[(size_t)(sp * FEA + o) * (NS * DIM) + n * DIM + d];
            v += pD[(size_t)(sp * FEA + o) * (NS * DIM) + n * DIM + d];
        }
        v = (v + h1t1[n * ELEMS + e]) * (1.0f / 3.0f);
        vals[e] = v; s1 += v; s2 += v * v;
    }
    float2 mr = block_meanrstd(s1, s2, tid, red8);
    for (int e = tid; e < ELEMS; e += 256) {
        out[n * ELEMS + e] = (vals[e] - mr.x) * mr.y;
    }
}

// xt[(f*32+i)*16+n] = x[(n*32+i)*192+f]
__global__ __launch_bounds__(256) void transpose_x(
    const float* __restrict__ x, float* __restrict__ xt)
{
    int idx = blockIdx.x * 256 + threadIdx.x;   // 98304 total
    int n = idx & 15;
    int r = idx >> 4;
    int i = r & 31;
    int f = r >> 5;
    xt[idx] = x[(n * 32 + i) * 192 + f];
}

// Y[r][j] = sum_f X[r][f] * M[f][j], 8 rows per block, 192 cols
__global__ __launch_bounds__(192) void mm192x8(
    const float* __restrict__ X, const float* __restrict__ M, float* __restrict__ Y)
{
    __shared__ float rows[8][192];
    const int rb = blockIdx.x * 8;
    const int j  = threadIdx.x;
#pragma unroll
    for (int k = 0; k < 8; ++k) rows[k][j] = X[(rb + k) * 192 + j];
    __syncthreads();
    float acc[8] = {0.f, 0.f, 0.f, 0.f, 0.f, 0.f, 0.f, 0.f};
    for (int f = 0; f < 192; ++f) {
        float m = M[f * 192 + j];
#pragma unroll
        for (int k = 0; k < 8; ++k) acc[k] = fmaf(rows[k][f], m, acc[k]);
    }
#pragma unroll
    for (int k = 0; k < 8; ++k) Y[(rb + k) * 192 + j] = acc[k];
}

extern "C" void kernel_launch(void* const* d_in, const int* in_sizes, int n_in,
                              void* d_out, int out_size, void* d_ws, size_t ws_size,
                              hipStream_t stream) {
    (void)in_sizes; (void)n_in; (void)out_size; (void)ws_size;
    const float* x   = (const float*)d_in[0];
    const float* s2t = (const float*)d_in[1];
    const float* t2s = (const float*)d_in[2];
    const float* s0  = (const float*)d_in[3];
    const float* s1  = (const float*)d_in[4];
    /* s2 = d_in[5] unused by the 4-layer schedule */
    const float* t0  = (const float*)d_in[6];
    const float* t1  = (const float*)d_in[7];
    const float* t2  = (const float*)d_in[8];
    float* out = (float*)d_out;

    float* ws = (float*)d_ws;
    float* xt   = ws; ws += 98304;
    float* xs1  = ws; ws += 98304;
    float* h1   = ws; ws += 98304;
    float* h1t  = ws; ws += 98304;
    float* h1t1 = ws; ws += 98304;
    float* h2t  = ws; ws += 98304;
    float* P    = ws; ws += SPLIT * FEA * NS * DIM;   // reused: pA -> pC -> pD
    float* pB   = ws; ws += SPLIT * FEA * NS * DIM;   // persists from E1 to final

    // Layer prep (depends only on x)
    transpose_x<<<384, 256, 0, stream>>>(x, xt);
    mm192x8<<<64, 192, 0, stream>>>(x, s1, xs1);          // xs1 = x @ s1

    // E1: one pass over s2t, two A-weighted outputs: (x,t0) -> h1 pre-LN, (x,t2) -> final term
    epass_kernel<true><<<768, TPB, 0, stream>>>(s2t, xt, t0, t2, P, pB);
    reduce_ln_h1<<<16, 256, 0, stream>>>(P, h1, h1t);     // h1 = LN(sum P)

    mm192x8<<<64, 192, 0, stream>>>(h1, t1, h1t1);        // h1t1 = h1 @ t1

    // E2: pass over t2s with h1, A = s0
    epass_kernel<false><<<768, TPB, 0, stream>>>(t2s, h1t, s0, nullptr, P, nullptr);
    reduce_ln_h2<<<16, 256, 0, stream>>>(P, xs1, h2t);    // h2 = LN(0.5*(xs1 + sum P))

    // E3: pass over s2t with h2, A = t0
    epass_kernel<false><<<768, TPB, 0, stream>>>(s2t, h2t, t0, nullptr, P, nullptr);

    // out = LN((pB + h1@t1 + pD)/3)
    final_ln<<<16, 256, 0, stream>>>(pB, P, h1t1, out);
}

// Round 3
// 607.747 us; speedup vs baseline: 1.6693x; 1.6693x over previous
//
#include <hip/hip_runtime.h>

// Problem dims
constexpr int NS   = 16;    // batch
constexpr int DIM  = 32;    // in_dim == out_dim
constexpr int FEA  = 192;   // in_f == out_f
constexpr int ELEMS = DIM * FEA;   // 6144 per sample

// epass tiling
constexpr int SPLIT   = 4;              // f-splits per o
constexpr int FPB     = FEA / SPLIT;    // 48 f per block
constexpr int FCHUNK  = 16;             // f per LDS stage
constexpr int NCHUNKS = FPB / FCHUNK;   // 3
constexpr int ROWPAD  = 20;             // 16 floats (n) + 4 pad
constexpr int TPB     = 512;            // epass threads per block
constexpr int FSTRIDE = FEA * DIM;      // advance one f in W (6144 floats)
constexpr int REDSTRIDE = 36;           // reduce row stride (16B aligned, 2-way banks)
constexpr int REDB      = 16 * 8 * REDSTRIDE;  // 4608 floats per (A/B) half

__device__ __forceinline__ void fma4(float4& a, float x, const float4& t) {
    a.x = fmaf(x, t.x, a.x);
    a.y = fmaf(x, t.y, a.y);
    a.z = fmaf(x, t.z, a.z);
    a.w = fmaf(x, t.w, a.w);
}

// One FCHUNK of the inner loop. tA/tB are a rolling 2-deep weight prefetch:
// the value consumed at step fl was loaded 2 steps earlier. LAST suppresses
// the final 2 loads (would run past W's end for i=31).
template <bool DUAL, bool LAST>
__device__ __forceinline__ void chunk_compute(
    const float* __restrict__ smem, const float* __restrict__ ac0,
    const float* __restrict__ ac1, int i, int nh,
    const float*& wp, float4& tA, float4& tB,
    float4* __restrict__ accA, float4* __restrict__ accB)
{
#pragma unroll
    for (int fl = 0; fl < FCHUNK; ++fl) {
        float4 cur = (fl & 1) ? tB : tA;
        if (!LAST || fl < FCHUNK - 2) {          // compile-time after unroll
            float4 nxt = *(const float4*)wp;
            wp += FSTRIDE;
            if (fl & 1) tB = nxt; else tA = nxt;
        }
        const float a1 = ac0[fl];
        float4 ta = make_float4(cur.x * a1, cur.y * a1, cur.z * a1, cur.w * a1);
        float4 tb;
        if (DUAL) {
            const float a2 = ac1[fl];
            tb = make_float4(cur.x * a2, cur.y * a2, cur.z * a2, cur.w * a2);
        }
        const float* xr = &smem[(fl * DIM + i) * ROWPAD + nh * 8];
        float4 xv0 = *(const float4*)xr;
        float4 xv1 = *(const float4*)(xr + 4);
        fma4(accA[0], xv0.x, ta);
        fma4(accA[1], xv0.y, ta);
        fma4(accA[2], xv0.z, ta);
        fma4(accA[3], xv0.w, ta);
        fma4(accA[4], xv1.x, ta);
        fma4(accA[5], xv1.y, ta);
        fma4(accA[6], xv1.z, ta);
        fma4(accA[7], xv1.w, ta);
        if (DUAL) {
            fma4(accB[0], xv0.x, tb);
            fma4(accB[1], xv0.y, tb);
            fma4(accB[2], xv0.z, tb);
            fma4(accB[3], xv0.w, tb);
            fma4(accB[4], xv1.x, tb);
            fma4(accB[5], xv1.y, tb);
            fma4(accB[6], xv1.z, tb);
            fma4(accB[7], xv1.w, tb);
        }
    }
}

// Weighted contraction:
//   y[n, D, O] = sum_{I=0..31, F} X[n,I,F] * W[I][F][O][D] * A[F][O]
// W layout: [32][192][192][32] (D contiguous)
// xt layout: [F][I][n] (n contiguous, 16)
// Output partials: out[s][O][n*32+D]  (512 floats per (s,O))
// Thread map: tid = i*16 + nh*8 + dq.  Each thread: 8 n (nh half) x 4 d (dq quad).
// NOTE: no min-waves hint — R1/R2 showed any occupancy cap makes the allocator
// halve the arch-VGPR budget (128/64) and spill the ~100-VGPR live set.
template <bool DUAL>
__global__ __launch_bounds__(TPB) void epass_kernel(
    const float* __restrict__ W, const float* __restrict__ xt,
    const float* __restrict__ A1, const float* __restrict__ A2,
    float* __restrict__ outA, float* __restrict__ outB)
{
    __shared__ float smem[FCHUNK * DIM * ROWPAD];  // 10240 floats (40 KB), reused for reduce
    __shared__ float acol[2][FPB];

    const int tid = threadIdx.x;
    const int o   = blockIdx.x >> 2;          // output O index
    const int s   = blockIdx.x & (SPLIT - 1); // f-split
    const int dq  = tid & 7;                  // D quad (0..7)
    const int nh  = (tid >> 3) & 1;           // n half (0..1)
    const int i   = tid >> 4;                 // contraction I (0..31)
    const int fBase = s * FPB;

    for (int j = tid; j < FPB; j += TPB) {
        acol[0][j] = A1[(fBase + j) * FEA + o];
        if (DUAL) acol[1][j] = A2[(fBase + j) * FEA + o];
    }

    float4 accA[8];
    float4 accB[8];
#pragma unroll
    for (int n = 0; n < 8; ++n) {
        accA[n] = make_float4(0.f, 0.f, 0.f, 0.f);
        if (DUAL) accB[n] = make_float4(0.f, 0.f, 0.f, 0.f);
    }

    const float* wp = W + (size_t)(((i * FEA + fBase) * FEA + o) * DIM + dq * 4);
    float4 tA = *(const float4*)wp; wp += FSTRIDE;   // fs=0
    float4 tB = *(const float4*)wp; wp += FSTRIDE;   // fs=1

    for (int c = 0; c < NCHUNKS; ++c) {
        __syncthreads();
        // Stage x chunk: 16 f x 32 i x 16 n = 8192 floats, contiguous in xt
        const float4* src = (const float4*)(xt + (size_t)(fBase + c * FCHUNK) * (DIM * NS));
#pragma unroll
        for (int q = 0; q < 4; ++q) {
            int lin = q * TPB + tid;            // quad index, 2048 total
            float4 v = src[lin];
            *(float4*)&smem[(lin >> 2) * ROWPAD + (lin & 3) * 4] = v;
        }
        __syncthreads();

        const float* ac0 = &acol[0][c * FCHUNK];
        const float* ac1 = &acol[1][c * FCHUNK];
        if (c < NCHUNKS - 1)
            chunk_compute<DUAL, false>(smem, ac0, ac1, i, nh, wp, tA, tB, accA, accB);
        else
            chunk_compute<DUAL, true>(smem, ac0, ac1, i, nh, wp, tA, tB, accA, accB);
    }

    // Reduce over i-low-2 (lane bits 4,5)
#pragma unroll
    for (int m = 16; m <= 32; m <<= 1) {
#pragma unroll
        for (int n = 0; n < 8; ++n) {
            accA[n].x += __shfl_xor(accA[n].x, m);
            accA[n].y += __shfl_xor(accA[n].y, m);
            accA[n].z += __shfl_xor(accA[n].z, m);
            accA[n].w += __shfl_xor(accA[n].w, m);
            if (DUAL) {
                accB[n].x += __shfl_xor(accB[n].x, m);
                accB[n].y += __shfl_xor(accB[n].y, m);
                accB[n].z += __shfl_xor(accB[n].z, m);
                accB[n].w += __shfl_xor(accB[n].w, m);
            }
        }
    }

    const int lane = tid & 63;
    const int w    = tid >> 6;     // wave = i high 3 bits
    float* red = smem;             // reuse staging LDS

    __syncthreads();
    if ((lane & 48) == 0) {
        const int base = (w * 16 + nh * 8 + dq) * REDSTRIDE;
#pragma unroll
        for (int n = 0; n < 8; ++n) {
            *(float4*)&red[base + n * 4] = accA[n];
            if (DUAL) *(float4*)&red[REDB + base + n * 4] = accB[n];
        }
    }
    __syncthreads();
    {
        const int h = tid;                 // 0..511 == NS*DIM
        const int n = h >> 5, d = h & 31;
        const int base = ((n >> 3) * 8 + (d >> 2)) * REDSTRIDE + (n & 7) * 4 + (d & 3);
        float v = 0.f, vb = 0.f;
#pragma unroll
        for (int w2 = 0; w2 < 8; ++w2) {
            v += red[w2 * 16 * REDSTRIDE + base];
            if (DUAL) vb += red[REDB + w2 * 16 * REDSTRIDE + base];
        }
        outA[(size_t)(s * FEA + o) * (NS * DIM) + h] = v;
        if (DUAL) outB[(size_t)(s * FEA + o) * (NS * DIM) + h] = vb;
    }
}

// ---- small helpers -------------------------------------------------------

__device__ __forceinline__ float2 block_meanrstd(float s1, float s2, int tid, float* red8) {
#pragma unroll
    for (int m = 1; m < 64; m <<= 1) {
        s1 += __shfl_xor(s1, m);
        s2 += __shfl_xor(s2, m);
    }
    if ((tid & 63) == 0) {
        red8[(tid >> 6) * 2]     = s1;
        red8[(tid >> 6) * 2 + 1] = s2;
    }
    __syncthreads();
    s1 = red8[0] + red8[2] + red8[4] + red8[6];
    s2 = red8[1] + red8[3] + red8[5] + red8[7];
    float mean = s1 * (1.0f / ELEMS);
    float var  = s2 * (1.0f / ELEMS) - mean * mean;
    return make_float2(mean, rsqrtf(var + 1e-5f));
}

// h1 = LN(sum_s pA); writes natural [n][D][O] and transposed [O][D][n]
__global__ __launch_bounds__(256) void reduce_ln_h1(
    const float* __restrict__ p, float* __restrict__ h1, float* __restrict__ h1t)
{
    __shared__ float vals[ELEMS];
    __shared__ float red8[8];
    const int n = blockIdx.x, tid = threadIdx.x;
    float s1 = 0.f, s2 = 0.f;
    for (int e = tid; e < ELEMS; e += 256) {
        int d = e / FEA, o = e % FEA;
        float v = 0.f;
#pragma unroll
        for (int sp = 0; sp < SPLIT; ++sp)
            v += p[(size_t)(sp * FEA + o) * (NS * DIM) + n * DIM + d];
        vals[e] = v; s1 += v; s2 += v * v;
    }
    float2 mr = block_meanrstd(s1, s2, tid, red8);
    for (int e = tid; e < ELEMS; e += 256) {
        float v = (vals[e] - mr.x) * mr.y;
        h1[n * ELEMS + e] = v;
        int d = e / FEA, o = e % FEA;
        h1t[(o * DIM + d) * NS + n] = v;
    }
}

// h2 = LN(0.5*(xs1 + sum_s pC)); writes transposed only
__global__ __launch_bounds__(256) void reduce_ln_h2(
    const float* __restrict__ p, const float* __restrict__ xs1, float* __restrict__ h2t)
{
    __shared__ float vals[ELEMS];
    __shared__ float red8[8];
    const int n = blockIdx.x, tid = threadIdx.x;
    float s1 = 0.f, s2 = 0.f;
    for (int e = tid; e < ELEMS; e += 256) {
        int d = e / FEA, o = e % FEA;
        float v = 0.f;
#pragma unroll
        for (int sp = 0; sp < SPLIT; ++sp)
            v += p[(size_t)(sp * FEA + o) * (NS * DIM) + n * DIM + d];
        v = 0.5f * (v + xs1[n * ELEMS + e]);
        vals[e] = v; s1 += v; s2 += v * v;
    }
    float2 mr = block_meanrstd(s1, s2, tid, red8);
    for (int e = tid; e < ELEMS; e += 256) {
        float v = (vals[e] - mr.x) * mr.y;
        int d = e / FEA, o = e % FEA;
        h2t[(o * DIM + d) * NS + n] = v;
    }
}

// out = LN((sum_s pB + h1t1 + sum_s pD)/3); natural layout
__global__ __launch_bounds__(256) void final_ln(
    const float* __restrict__ pB, const float* __restrict__ pD,
    const float* __restrict__ h1t1, float* __restrict__ out)
{
    __shared__ float vals[ELEMS];
    __shared__ float red8[8];
    const int n = blockIdx.x, tid = threadIdx.x;
    float s1 = 0.f, s2 = 0.f;
    for (int e = tid; e < ELEMS; e += 256) {
        int d = e / FEA, o = e % FEA;
        float v = 0.f;
#pragma unroll
        for (int sp = 0; sp < SPLIT; ++sp) {
            v += pB[(size_t)(sp * FEA + o) * (NS * DIM) + n * DIM + d];
            v += pD[(size_t)(sp * FEA + o) * (NS * DIM) + n * DIM + d];
        }
        v = (v + h1t1[n * ELEMS + e]) * (1.0f / 3.0f);
        vals[e] = v; s1 += v; s2 += v * v;
    }
    float2 mr = block_meanrstd(s1, s2, tid, red8);
    for (int e = tid; e < ELEMS; e += 256) {
        out[n * ELEMS + e] = (vals[e] - mr.x) * mr.y;
    }
}

// xt[(f*32+i)*16+n] = x[(n*32+i)*192+f]
__global__ __launch_bounds__(256) void transpose_x(
    const float* __restrict__ x, float* __restrict__ xt)
{
    int idx = blockIdx.x * 256 + threadIdx.x;   // 98304 total
    int n = idx & 15;
    int r = idx >> 4;
    int i = r & 31;
    int f = r >> 5;
    xt[idx] = x[(n * 32 + i) * 192 + f];
}

// Y[r][j] = sum_f X[r][f] * M[f][j], 8 rows per block, 192 cols
__global__ __launch_bounds__(192) void mm192x8(
    const float* __restrict__ X, const float* __restrict__ M, float* __restrict__ Y)
{
    __shared__ float rows[8][192];
    const int rb = blockIdx.x * 8;
    const int j  = threadIdx.x;
#pragma unroll
    for (int k = 0; k < 8; ++k) rows[k][j] = X[(rb + k) * 192 + j];
    __syncthreads();
    float acc[8] = {0.f, 0.f, 0.f, 0.f, 0.f, 0.f, 0.f, 0.f};
    for (int f = 0; f < 192; ++f) {
        float m = M[f * 192 + j];
#pragma unroll
        for (int k = 0; k < 8; ++k) acc[k] = fmaf(rows[k][f], m, acc[k]);
    }
#pragma unroll
    for (int k = 0; k < 8; ++k) Y[(rb + k) * 192 + j] = acc[k];
}

extern "C" void kernel_launch(void* const* d_in, const int* in_sizes, int n_in,
                              void* d_out, int out_size, void* d_ws, size_t ws_size,
                              hipStream_t stream) {
    (void)in_sizes; (void)n_in; (void)out_size; (void)ws_size;
    const float* x   = (const float*)d_in[0];
    const float* s2t = (const float*)d_in[1];
    const float* t2s = (const float*)d_in[2];
    const float* s0  = (const float*)d_in[3];
    const float* s1  = (const float*)d_in[4];
    /* s2 = d_in[5] unused by the 4-layer schedule */
    const float* t0  = (const float*)d_in[6];
    const float* t1  = (const float*)d_in[7];
    const float* t2  = (const float*)d_in[8];
    float* out = (float*)d_out;

    float* ws = (float*)d_ws;
    float* xt   = ws; ws += 98304;
    float* xs1  = ws; ws += 98304;
    float* h1   = ws; ws += 98304;
    float* h1t  = ws; ws += 98304;
    float* h1t1 = ws; ws += 98304;
    float* h2t  = ws; ws += 98304;
    float* P    = ws; ws += SPLIT * FEA * NS * DIM;   // reused: pA -> pC -> pD
    float* pB   = ws; ws += SPLIT * FEA * NS * DIM;   // persists from E1 to final

    // Layer prep (depends only on x)
    transpose_x<<<384, 256, 0, stream>>>(x, xt);
    mm192x8<<<64, 192, 0, stream>>>(x, s1, xs1);          // xs1 = x @ s1

    // E1: one pass over s2t, two A-weighted outputs: (x,t0) -> h1 pre-LN, (x,t2) -> final term
    epass_kernel<true><<<768, TPB, 0, stream>>>(s2t, xt, t0, t2, P, pB);
    reduce_ln_h1<<<16, 256, 0, stream>>>(P, h1, h1t);     // h1 = LN(sum P)

    mm192x8<<<64, 192, 0, stream>>>(h1, t1, h1t1);        // h1t1 = h1 @ t1

    // E2: pass over t2s with h1, A = s0
    epass_kernel<false><<<768, TPB, 0, stream>>>(t2s, h1t, s0, nullptr, P, nullptr);
    reduce_ln_h2<<<16, 256, 0, stream>>>(P, xs1, h2t);    // h2 = LN(0.5*(xs1 + sum P))

    // E3: pass over s2t with h2, A = t0
    epass_kernel<false><<<768, TPB, 0, stream>>>(s2t, h2t, t0, nullptr, P, nullptr);

    // out = LN((pB + h1@t1 + pD)/3)
    final_ln<<<16, 256, 0, stream>>>(pB, P, h1t1, out);
}

// Round 4
// 500.026 us; speedup vs baseline: 2.0289x; 1.2154x over previous
//
#include <hip/hip_runtime.h>

// Problem dims
constexpr int NS   = 16;    // batch
constexpr int DIM  = 32;    // in_dim == out_dim
constexpr int FEA  = 192;   // in_f == out_f
constexpr int ELEMS = DIM * FEA;   // 6144 per sample

// epass tiling
constexpr int SPLIT   = 4;              // f-splits per o
constexpr int FPB     = FEA / SPLIT;    // 48 f per block
constexpr int FCHUNK  = 16;             // f per LDS stage
constexpr int NCHUNKS = FPB / FCHUNK;   // 3
constexpr int ROWPAD  = 20;             // 16 floats (n) + 4 pad
constexpr int TPB     = 1024;           // epass threads per block
constexpr int FSTRIDE = FEA * DIM;      // advance one f in W (6144 floats)

__device__ __forceinline__ void fma4(float4& a, float x, const float4& t) {
    a.x = fmaf(x, t.x, a.x);
    a.y = fmaf(x, t.y, a.y);
    a.z = fmaf(x, t.z, a.z);
    a.w = fmaf(x, t.w, a.w);
}

// One FCHUNK of the inner loop. tA/tB: rolling 2-deep weight prefetch.
// LAST suppresses the final 2 loads (would run past W's end for i=31).
template <bool DUAL, bool LAST>
__device__ __forceinline__ void chunk_compute(
    const float* __restrict__ smem, const float* __restrict__ ac0,
    const float* __restrict__ ac1, int i, int np,
    const float*& wp, float4& tA, float4& tB,
    float4* __restrict__ accA, float4* __restrict__ accB)
{
#pragma unroll
    for (int fl = 0; fl < FCHUNK; ++fl) {
        float4 cur = (fl & 1) ? tB : tA;
        if (!LAST || fl < FCHUNK - 2) {          // compile-time after unroll
            float4 nxt = *(const float4*)wp;
            wp += FSTRIDE;
            if (fl & 1) tB = nxt; else tA = nxt;
        }
        const float a1 = ac0[fl];
        float4 ta = make_float4(cur.x * a1, cur.y * a1, cur.z * a1, cur.w * a1);
        float4 tb;
        if (DUAL) {
            const float a2 = ac1[fl];
            tb = make_float4(cur.x * a2, cur.y * a2, cur.z * a2, cur.w * a2);
        }
        float4 xv = *(const float4*)&smem[(fl * DIM + i) * ROWPAD + np * 4];
        fma4(accA[0], xv.x, ta);
        fma4(accA[1], xv.y, ta);
        fma4(accA[2], xv.z, ta);
        fma4(accA[3], xv.w, ta);
        if (DUAL) {
            fma4(accB[0], xv.x, tb);
            fma4(accB[1], xv.y, tb);
            fma4(accB[2], xv.z, tb);
            fma4(accB[3], xv.w, tb);
        }
    }
}

// Weighted contraction:
//   y[n, D, O] = sum_{I=0..31, F} X[n,I,F] * W[I][F][O][D] * A[F][O]
// W layout: [32][192][192][32] (D contiguous)
// X layout: NATURAL [n][I][F] — the stager transposes into LDS [F][I][n].
// Output partials: out[s][O][n*32+D]  (512 floats per (s,O))
// Thread map: tid = i*32 + np*8 + dq. Each thread: 4 n (np quarter) x 4 d (dq quad).
template <bool DUAL>
__global__ __launch_bounds__(TPB) void epass_kernel(
    const float* __restrict__ W, const float* __restrict__ X,
    const float* __restrict__ A1, const float* __restrict__ A2,
    float* __restrict__ outA, float* __restrict__ outB)
{
    __shared__ float smem[FCHUNK * DIM * ROWPAD];  // 10240 floats; reused for reduce
    __shared__ float acol[2][FPB];

    const int tid = threadIdx.x;
    const int o   = blockIdx.x >> 2;          // output O index
    const int s   = blockIdx.x & (SPLIT - 1); // f-split
    const int dq  = tid & 7;                  // D quad (0..7)
    const int np  = (tid >> 3) & 3;           // n quarter (0..3)
    const int i   = tid >> 5;                 // contraction I (0..31)
    const int fBase = s * FPB;

    if (tid < FPB) {
        acol[0][tid] = A1[(fBase + tid) * FEA + o];
        if (DUAL) acol[1][tid] = A2[(fBase + tid) * FEA + o];
    }

    float4 accA[4];
    float4 accB[4];
#pragma unroll
    for (int j = 0; j < 4; ++j) {
        accA[j] = make_float4(0.f, 0.f, 0.f, 0.f);
        if (DUAL) accB[j] = make_float4(0.f, 0.f, 0.f, 0.f);
    }

    const float* wp = W + (size_t)(((i * FEA + fBase) * FEA + o) * DIM + dq * 4);
    float4 tA = *(const float4*)wp; wp += FSTRIDE;   // fs=0
    float4 tB = *(const float4*)wp; wp += FSTRIDE;   // fs=1

    for (int c = 0; c < NCHUNKS; ++c) {
        __syncthreads();
        // Stage x chunk from NATURAL layout: 16 f x 32 i x 16 n
#pragma unroll
        for (int r = 0; r < 2; ++r) {
            int q  = r * TPB + tid;             // 2048 float4 total
            int nn = q >> 7;                    // 0..15
            int ii = (q >> 2) & 31;             // 0..31
            int fq = q & 3;                     // f quad within chunk
            float4 v = *(const float4*)(X + (size_t)(nn * DIM + ii) * FEA
                                          + fBase + c * FCHUNK + fq * 4);
            smem[((fq * 4 + 0) * DIM + ii) * ROWPAD + nn] = v.x;
            smem[((fq * 4 + 1) * DIM + ii) * ROWPAD + nn] = v.y;
            smem[((fq * 4 + 2) * DIM + ii) * ROWPAD + nn] = v.z;
            smem[((fq * 4 + 3) * DIM + ii) * ROWPAD + nn] = v.w;
        }
        __syncthreads();

        const float* ac0 = &acol[0][c * FCHUNK];
        const float* ac1 = &acol[1][c * FCHUNK];
        if (c < NCHUNKS - 1)
            chunk_compute<DUAL, false>(smem, ac0, ac1, i, np, wp, tA, tB, accA, accB);
        else
            chunk_compute<DUAL, true>(smem, ac0, ac1, i, np, wp, tA, tB, accA, accB);
    }

    // Reduce over i parity (lane bit 5)
#pragma unroll
    for (int j = 0; j < 4; ++j) {
        accA[j].x += __shfl_xor(accA[j].x, 32);
        accA[j].y += __shfl_xor(accA[j].y, 32);
        accA[j].z += __shfl_xor(accA[j].z, 32);
        accA[j].w += __shfl_xor(accA[j].w, 32);
        if (DUAL) {
            accB[j].x += __shfl_xor(accB[j].x, 32);
            accB[j].y += __shfl_xor(accB[j].y, 32);
            accB[j].z += __shfl_xor(accB[j].z, 32);
            accB[j].w += __shfl_xor(accB[j].w, 32);
        }
    }

    const int lane = tid & 63;
    const int wv   = tid >> 6;     // 16 waves, wave holds i pair {2wv, 2wv+1}
    float* red = smem;             // reuse staging LDS: 16 x 32 x ROWPAD = 10240

    __syncthreads();
    if (!(lane & 32)) {
        const int base = (wv * 32 + lane) * ROWPAD;   // lane<32 encodes (np,dq)
#pragma unroll
        for (int j = 0; j < 4; ++j)
            *(float4*)&red[base + j * 4] = accA[j];
    }
    __syncthreads();
    if (tid < NS * DIM) {
        const int n = tid >> 5, d = tid & 31;
        const int li  = (n >> 2) * 8 + (d >> 2);      // (np,dq) slot
        const int off = (n & 3) * 4 + (d & 3);        // (j,k) within row
        float v = 0.f;
#pragma unroll
        for (int w2 = 0; w2 < 16; ++w2)
            v += red[(w2 * 32 + li) * ROWPAD + off];
        outA[(size_t)(s * FEA + o) * (NS * DIM) + tid] = v;
    }
    if (DUAL) {
        __syncthreads();
        if (!(lane & 32)) {
            const int base = (wv * 32 + lane) * ROWPAD;
#pragma unroll
            for (int j = 0; j < 4; ++j)
                *(float4*)&red[base + j * 4] = accB[j];
        }
        __syncthreads();
        if (tid < NS * DIM) {
            const int n = tid >> 5, d = tid & 31;
            const int li  = (n >> 2) * 8 + (d >> 2);
            const int off = (n & 3) * 4 + (d & 3);
            float v = 0.f;
#pragma unroll
            for (int w2 = 0; w2 < 16; ++w2)
                v += red[(w2 * 32 + li) * ROWPAD + off];
            outB[(size_t)(s * FEA + o) * (NS * DIM) + tid] = v;
        }
    }
}

// ---- LN helpers (512-thread blocks) --------------------------------------

__device__ __forceinline__ float2 ln_stats_512(float s1, float s2, int tid, float* red) {
#pragma unroll
    for (int m = 1; m < 64; m <<= 1) {
        s1 += __shfl_xor(s1, m);
        s2 += __shfl_xor(s2, m);
    }
    if ((tid & 63) == 0) {
        red[(tid >> 6) * 2]     = s1;
        red[(tid >> 6) * 2 + 1] = s2;
    }
    __syncthreads();
    float a = 0.f, b = 0.f;
#pragma unroll
    for (int ww = 0; ww < 8; ++ww) { a += red[ww * 2]; b += red[ww * 2 + 1]; }
    float mean = a * (1.0f / ELEMS);
    float var  = b * (1.0f / ELEMS) - mean * mean;
    return make_float2(mean, rsqrtf(var + 1e-5f));
}

// h1 = LN(sum_s P). P layout [s][o][n*32+d]; output natural [n][d][o].
__global__ __launch_bounds__(512) void reduce_ln_h1(
    const float* __restrict__ p, float* __restrict__ h1)
{
    __shared__ float vals[FEA * 33];   // [o][d] padded
    __shared__ float red[16];
    const int n = blockIdx.x, tid = threadIdx.x;
    float s1 = 0.f, s2 = 0.f;
    for (int e = tid; e < ELEMS; e += 512) {      // d fast -> coalesced P reads
        int d = e & 31, o = e >> 5;
        float v = 0.f;
#pragma unroll
        for (int sp = 0; sp < SPLIT; ++sp)
            v += p[(size_t)(sp * FEA + o) * (NS * DIM) + n * DIM + d];
        vals[o * 33 + d] = v; s1 += v; s2 += v * v;
    }
    float2 mr = ln_stats_512(s1, s2, tid, red);
    for (int e = tid; e < ELEMS; e += 512) {      // o fast -> coalesced h1 writes
        int o = e % FEA, d = e / FEA;
        h1[(size_t)n * ELEMS + e] = (vals[o * 33 + d] - mr.x) * mr.y;
    }
}

// h2 = LN(0.5*(xs1 + sum_s P)); output natural [n][e][f].
__global__ __launch_bounds__(512) void reduce_ln_h2(
    const float* __restrict__ p, const float* __restrict__ xs1, float* __restrict__ h2)
{
    __shared__ float vals[FEA * 33];
    __shared__ float red[16];
    const int n = blockIdx.x, tid = threadIdx.x;
    for (int e = tid; e < ELEMS; e += 512) {
        int d = e & 31, o = e >> 5;
        float v = 0.f;
#pragma unroll
        for (int sp = 0; sp < SPLIT; ++sp)
            v += p[(size_t)(sp * FEA + o) * (NS * DIM) + n * DIM + d];
        vals[o * 33 + d] = v;
    }
    __syncthreads();
    float s1 = 0.f, s2 = 0.f;
    for (int e = tid; e < ELEMS; e += 512) {      // natural order for xs1
        int o = e % FEA, d = e / FEA;
        float v = 0.5f * (vals[o * 33 + d] + xs1[(size_t)n * ELEMS + e]);
        vals[o * 33 + d] = v; s1 += v; s2 += v * v;
    }
    float2 mr = ln_stats_512(s1, s2, tid, red);
    for (int e = tid; e < ELEMS; e += 512) {
        int o = e % FEA, d = e / FEA;
        h2[(size_t)n * ELEMS + e] = (vals[o * 33 + d] - mr.x) * mr.y;
    }
}

// out = LN((sum_s pB + sum_s pD + h1t1)/3); output natural [n][d][o].
__global__ __launch_bounds__(512) void final_ln(
    const float* __restrict__ pB, const float* __restrict__ pD,
    const float* __restrict__ h1t1, float* __restrict__ out)
{
    __shared__ float vals[FEA * 33];
    __shared__ float red[16];
    const int n = blockIdx.x, tid = threadIdx.x;
    for (int e = tid; e < ELEMS; e += 512) {
        int d = e & 31, o = e >> 5;
        float v = 0.f;
#pragma unroll
        for (int sp = 0; sp < SPLIT; ++sp) {
            v += pB[(size_t)(sp * FEA + o) * (NS * DIM) + n * DIM + d];
            v += pD[(size_t)(sp * FEA + o) * (NS * DIM) + n * DIM + d];
        }
        vals[o * 33 + d] = v;
    }
    __syncthreads();
    float s1 = 0.f, s2 = 0.f;
    for (int e = tid; e < ELEMS; e += 512) {
        int o = e % FEA, d = e / FEA;
        float v = (vals[o * 33 + d] + h1t1[(size_t)n * ELEMS + e]) * (1.0f / 3.0f);
        vals[o * 33 + d] = v; s1 += v; s2 += v * v;
    }
    float2 mr = ln_stats_512(s1, s2, tid, red);
    for (int e = tid; e < ELEMS; e += 512) {
        int o = e % FEA, d = e / FEA;
        out[(size_t)n * ELEMS + e] = (vals[o * 33 + d] - mr.x) * mr.y;
    }
}

// Y[r][j] = sum_f X[r][f] * M[f][j], 8 rows per block, 192 cols
__global__ __launch_bounds__(192) void mm192x8(
    const float* __restrict__ X, const float* __restrict__ M, float* __restrict__ Y)
{
    __shared__ float rows[8][192];
    const int rb = blockIdx.x * 8;
    const int j  = threadIdx.x;
#pragma unroll
    for (int k = 0; k < 8; ++k) rows[k][j] = X[(rb + k) * 192 + j];
    __syncthreads();
    float acc[8] = {0.f, 0.f, 0.f, 0.f, 0.f, 0.f, 0.f, 0.f};
    for (int f = 0; f < 192; ++f) {
        float m = M[f * 192 + j];
#pragma unroll
        for (int k = 0; k < 8; ++k) acc[k] = fmaf(rows[k][f], m, acc[k]);
    }
#pragma unroll
    for (int k = 0; k < 8; ++k) Y[(rb + k) * 192 + j] = acc[k];
}

extern "C" void kernel_launch(void* const* d_in, const int* in_sizes, int n_in,
                              void* d_out, int out_size, void* d_ws, size_t ws_size,
                              hipStream_t stream) {
    (void)in_sizes; (void)n_in; (void)out_size; (void)ws_size;
    const float* x   = (const float*)d_in[0];
    const float* s2t = (const float*)d_in[1];
    const float* t2s = (const float*)d_in[2];
    const float* s0  = (const float*)d_in[3];
    const float* s1  = (const float*)d_in[4];
    /* s2 = d_in[5] unused by the 4-layer schedule */
    const float* t0  = (const float*)d_in[6];
    const float* t1  = (const float*)d_in[7];
    const float* t2  = (const float*)d_in[8];
    float* out = (float*)d_out;

    float* ws = (float*)d_ws;
    float* xs1  = ws; ws += 98304;
    float* h1   = ws; ws += 98304;
    float* h1t1 = ws; ws += 98304;
    float* h2   = ws; ws += 98304;
    float* P    = ws; ws += SPLIT * FEA * NS * DIM;   // reused: pA -> pC -> pD
    float* pB   = ws; ws += SPLIT * FEA * NS * DIM;   // persists from E1 to final

    mm192x8<<<64, 192, 0, stream>>>(x, s1, xs1);          // xs1 = x @ s1

    // E1: one pass over s2t, two A-weighted outputs: (x,t0) -> h1 pre-LN, (x,t2) -> final term
    epass_kernel<true><<<768, TPB, 0, stream>>>(s2t, x, t0, t2, P, pB);
    reduce_ln_h1<<<16, 512, 0, stream>>>(P, h1);          // h1 = LN(sum P), natural layout

    mm192x8<<<64, 192, 0, stream>>>(h1, t1, h1t1);        // h1t1 = h1 @ t1

    // E2: pass over t2s with h1 (natural layout), A = s0
    epass_kernel<false><<<768, TPB, 0, stream>>>(t2s, h1, s0, nullptr, P, nullptr);
    reduce_ln_h2<<<16, 512, 0, stream>>>(P, xs1, h2);     // h2 = LN(0.5*(xs1 + sum P))

    // E3: pass over s2t with h2 (natural layout), A = t0
    epass_kernel<false><<<768, TPB, 0, stream>>>(s2t, h2, t0, nullptr, P, nullptr);

    // out = LN((pB + h1@t1 + pD)/3)
    final_ln<<<16, 512, 0, stream>>>(pB, P, h1t1, out);
}